// Round 16
// baseline (178.717 us; speedup 1.0000x reference)
//
#include <hip/hip_runtime.h>

#define NC 20
#define THREADS 256
#define BLOCKS 2048
#define GRAN 8             // int4 granules/thread: 2048*256*8 = 4,194,304 = n/4 exactly
#define EPSF 1e-10f
#define NSLOT 64           // accumulator slots per counter: contention depth 32
#define NSUB 32            // sub-counters: depth 64; master: depth 32

typedef unsigned long long u64;
typedef unsigned int u32;
typedef int  v4i __attribute__((ext_vector_type(4)));

// ws layout (u32 idx): [0,3840) acc[60][64]; [3840,3872) cnt1[32]; [3872] cnt2
// fallback path reuses [0,60) as gc[60].
#define ACC_WORDS (60 * NSLOT)
#define WS_ZERO_BYTES ((ACC_WORDS + NSUB + 1) * 4)

// One-hot (3-bit fields, 20 classes in 60 bits) accumulate for one pair.
static __device__ __forceinline__ void pair_update(int p, int t,
                                                   u64& np, u64& nt, u64& ne)
{
    u64 ip = 1ull << (3 * p);
    u64 it = 1ull << (3 * t);
    np += ip;
    nt += it;
    ne += (p == t) ? ip : 0ull;   // branchless
}

// Fully fused: bit-sliced count + slot-spread atomic accumulate + hierarchical
// last-block detection + in-kernel finalize. ONE big dispatch.
__global__ __launch_bounds__(THREADS) void dice_fused(
    const int* __restrict__ pred, const int* __restrict__ tgt,
    u32* __restrict__ acc, u32* __restrict__ cnt1, u32* __restrict__ cnt2,
    float* __restrict__ out)
{
    constexpr u64 M = 0x01C71C71C71C71C7ull;  // 6-bit-spaced 3-bit mask (10 slots)
    __shared__ u32 swave[4][30];
    __shared__ u32 amLast;
    __shared__ u32 cls[64];
    const int tid = threadIdx.x;
    const int g   = blockIdx.x * THREADS + tid;
    const int S   = BLOCKS * THREADS;
    const v4i* p4 = (const v4i*)pred;
    const v4i* t4 = (const v4i*)tgt;

    // ---- stage 1: bit-sliced counting (R15 verbatim, nt loads) ----
    u64 aeP=0, aoP=0, aeT=0, aoT=0, aeE=0, aoE=0;
    #pragma unroll
    for (int k = 0; k < GRAN; ++k) {
        v4i P = __builtin_nontemporal_load(&p4[g + k * S]);
        v4i T = __builtin_nontemporal_load(&t4[g + k * S]);
        u64 np = 0, nt = 0, ne = 0;   // in-granule 3-bit fields (max 4 <= 7)
        pair_update(P.x, T.x, np, nt, ne);
        pair_update(P.y, T.y, np, nt, ne);
        pair_update(P.z, T.z, np, nt, ne);
        pair_update(P.w, T.w, np, nt, ne);
        aeP += np & M;        aoP += (np >> 3) & M;
        aeT += nt & M;        aoT += (nt >> 3) & M;
        aeE += ne & M;        aoE += (ne >> 3) & M;
    }

    const int wid  = tid >> 6;
    const int lane = tid & 63;
    #pragma unroll
    for (int j = 0; j < 10; ++j) {
        const int sh = 6 * j;
        u32 sP = (u32)((aeP >> sh) & 63) | ((u32)((aoP >> sh) & 63) << 16);
        u32 sT = (u32)((aeT >> sh) & 63) | ((u32)((aoT >> sh) & 63) << 16);
        u32 sE = (u32)((aeE >> sh) & 63) | ((u32)((aoE >> sh) & 63) << 16);
        #pragma unroll
        for (int d = 32; d >= 1; d >>= 1) {
            sP += __shfl_down(sP, d, 64);
            sT += __shfl_down(sT, d, 64);
            sE += __shfl_down(sE, d, 64);
        }
        if (lane == 0) {
            swave[wid][j]      = sP;
            swave[wid][10 + j] = sT;
            swave[wid][20 + j] = sE;
        }
    }
    __syncthreads();

    // ---- block result -> slot-spread device accumulators (depth 32/addr) ----
    // wave 0 only (tid<30): two atomicAdds each; then tid0 fences (wave-level
    // vmcnt covers all lanes' adds) and climbs the counter hierarchy.
    if (tid < 30) {
        u32 s = swave[0][tid] + swave[1][tid] + swave[2][tid] + swave[3][tid];
        const int h  = tid / 10, kk = tid % 10;
        const int slot = blockIdx.x & (NSLOT - 1);
        atomicAdd(&acc[(h * 20 + 2 * kk)     * NSLOT + slot], s & 0xFFFFu);
        atomicAdd(&acc[(h * 20 + 2 * kk + 1) * NSLOT + slot], s >> 16);
    }
    if (tid == 0) {
        __threadfence();   // drain wave-0 vmem (the 60 adds) + device fence
        u32 last = 0;
        u32 o1 = __hip_atomic_fetch_add(&cnt1[blockIdx.x & (NSUB - 1)], 1u,
                                        __ATOMIC_ACQ_REL, __HIP_MEMORY_SCOPE_AGENT);
        if (o1 == (BLOCKS / NSUB) - 1) {   // last arrival at this sub-counter
            u32 o2 = __hip_atomic_fetch_add(cnt2, 1u,
                                            __ATOMIC_ACQ_REL, __HIP_MEMORY_SCOPE_AGENT);
            last = (o2 == NSUB - 1);       // globally last block
        }
        amLast = last;
    }
    __syncthreads();
    if (!amLast) return;

    // ---- tail (last block only): sum 60 counters x 64 slots = 15 KB ----
    if (tid < 240) {
        const int j = tid >> 2;            // counter 0..59 (= h*20 + class)
        const int q = tid & 3;
        u32 s = 0;
        #pragma unroll
        for (int i = 0; i < 16; ++i)
            s += __hip_atomic_load(&acc[j * NSLOT + q * 16 + i],
                                   __ATOMIC_RELAXED, __HIP_MEMORY_SCOPE_AGENT);
        s += __shfl_down(s, 2, 4);
        s += __shfl_down(s, 1, 4);
        if (q == 0) cls[j] = s;
    }
    __syncthreads();
    if (tid < 64) {
        const int c = tid;                 // classes 1..19 contribute
        float contrib = 0.0f;
        if (c >= 1 && c < NC) {
            float pc = (float)cls[c];
            float tc = (float)cls[20 + c];
            float tp = (float)cls[40 + c];
            contrib = 2.0f * tp / (pc + tc + EPSF);
        }
        #pragma unroll
        for (int d = 32; d >= 1; d >>= 1) contrib += __shfl_down(contrib, d, 64);
        if (tid == 0) out[0] = contrib * (1.0f / 19.0f);
    }
}

// Generic fallback (any n divisible by 4): joint-histogram kernel w/ atomics.
__global__ __launch_bounds__(THREADS) void dice_joint(
    const int* __restrict__ pred, const int* __restrict__ tgt,
    u32* __restrict__ gc, long long n4)
{
    __shared__ u32 h[4 * NC * NC];
    const int tid = threadIdx.x;
    for (int k = tid; k < 4 * NC * NC; k += THREADS) h[k] = 0u;
    __syncthreads();
    u32* hw = &h[(tid >> 6) * NC * NC];
    const int4* p4 = (const int4*)pred;
    const int4* t4 = (const int4*)tgt;
    const long long stride = (long long)2048 * THREADS;
    for (long long i = (long long)blockIdx.x * THREADS + tid; i < n4; i += stride) {
        int4 Pv = p4[i];
        int4 Tv = t4[i];
        atomicAdd(&hw[Pv.x * NC + Tv.x], 1u);
        atomicAdd(&hw[Pv.y * NC + Tv.y], 1u);
        atomicAdd(&hw[Pv.z * NC + Tv.z], 1u);
        atomicAdd(&hw[Pv.w * NC + Tv.w], 1u);
    }
    __syncthreads();
    for (int k = tid; k < NC * NC; k += THREADS)
        h[k] = h[k] + h[NC*NC + k] + h[2*NC*NC + k] + h[3*NC*NC + k];
    __syncthreads();
    if (tid < 3 * (NC - 1)) {
        const int which = tid / (NC - 1);
        const int c     = tid % (NC - 1) + 1;
        u32 s = 0;
        if (which == 0)      { for (int t = 0; t < NC; ++t) s += h[c * NC + t]; }
        else if (which == 1) { for (int p = 0; p < NC; ++p) s += h[p * NC + c]; }
        else                 { s = h[c * NC + c]; }
        atomicAdd(&gc[which * NC + c], s);
    }
}

__global__ void dice_final(const u32* __restrict__ gc, float* __restrict__ out)
{
    const int c = threadIdx.x;
    float contrib = 0.0f;
    if (c >= 1 && c < NC) {
        float pc = (float)gc[c];
        float tc = (float)gc[NC + c];
        float tp = (float)gc[2 * NC + c];
        contrib = 2.0f * tp / (pc + tc + EPSF);
    }
    #pragma unroll
    for (int d = 32; d >= 1; d >>= 1) contrib += __shfl_down(contrib, d, 64);
    if (c == 0) out[0] = contrib * (1.0f / 19.0f);
}

extern "C" void kernel_launch(void* const* d_in, const int* in_sizes, int n_in,
                              void* d_out, int out_size, void* d_ws, size_t ws_size,
                              hipStream_t stream) {
    const int* pred = (const int*)d_in[0];
    const int* tgt  = (const int*)d_in[1];
    u32* acc  = (u32*)d_ws;
    u32* cnt1 = acc + ACC_WORDS;
    u32* cnt2 = cnt1 + NSUB;

    const int n  = in_sizes[0];        // 16,777,216
    const int n4 = n >> 2;             // 4,194,304 == BLOCKS*THREADS*GRAN

    if (n4 == BLOCKS * THREADS * GRAN && ws_size >= (size_t)WS_ZERO_BYTES) {
        // Zero accumulators + counters (15.5 KB), then ONE fused dispatch.
        (void)hipMemsetAsync(d_ws, 0, WS_ZERO_BYTES, stream);
        dice_fused<<<BLOCKS, THREADS, 0, stream>>>(pred, tgt, acc, cnt1, cnt2,
                                                   (float*)d_out);
    } else {
        (void)hipMemsetAsync(d_ws, 0, 3 * NC * sizeof(u32), stream);
        dice_joint<<<2048, THREADS, 0, stream>>>(pred, tgt, acc, (long long)n4);
        dice_final<<<1, 64, 0, stream>>>(acc, (float*)d_out);
    }
}

// Round 17
// 35.669 us; speedup vs baseline: 5.0104x; 5.0104x over previous
//
#include <hip/hip_runtime.h>

#define NC 20
#define THREADS 256
#define BLOCKS 2048
#define GRAN 8             // int4 granules/thread: 2048*256*8 = 4,194,304 = n/4 exactly
#define EPSF 1e-10f

typedef unsigned long long u64;
typedef unsigned int u32;
typedef int  v4i __attribute__((ext_vector_type(4)));   // nt-load-compatible
typedef u32  v4u __attribute__((ext_vector_type(4)));

// ws layout: [0,240): u32 gc[60] (fallback path); [256B on): part[30][BLOCKS]
#define PART_OFF 64        // in u32s
#define WS_NEEDED (256 + 30 * BLOCKS * 4)

// One-hot (3-bit fields, 20 classes in 60 bits) accumulate for one pair.
static __device__ __forceinline__ void pair_update(int p, int t,
                                                   u64& np, u64& nt, u64& ne)
{
    u64 ip = 1ull << (3 * p);
    u64 it = 1ull << (3 * t);
    np += ip;
    nt += it;
    ne += (p == t) ? ip : 0ull;   // branchless
}

// Stage 1: bit-sliced counting with non-temporal loads (stream is never
// re-read; nt skips L2 allocation). Partials STORED per block -- zero
// contended atomics, zero device-scope fences (R16 showed those cost 5x).
__global__ __launch_bounds__(THREADS) void dice_slice(
    const int* __restrict__ pred, const int* __restrict__ tgt,
    u32* __restrict__ part)
{
    constexpr u64 M = 0x01C71C71C71C71C7ull;  // 6-bit-spaced 3-bit mask (10 slots)
    __shared__ u32 swave[4][30];
    const int tid = threadIdx.x;
    const int g   = blockIdx.x * THREADS + tid;
    const int S   = BLOCKS * THREADS;
    const v4i* p4 = (const v4i*)pred;
    const v4i* t4 = (const v4i*)tgt;

    // 6-bit-spaced accumulators, even classes in *e*, odd in *o*.
    // Per-class per-thread max = GRAN*4 = 32 <= 63: no overflow.
    u64 aeP=0, aoP=0, aeT=0, aoT=0, aeE=0, aoE=0;

    #pragma unroll
    for (int k = 0; k < GRAN; ++k) {
        v4i P = __builtin_nontemporal_load(&p4[g + k * S]);
        v4i T = __builtin_nontemporal_load(&t4[g + k * S]);
        u64 np = 0, nt = 0, ne = 0;   // in-granule 3-bit fields (max 4 <= 7)
        pair_update(P.x, T.x, np, nt, ne);
        pair_update(P.y, T.y, np, nt, ne);
        pair_update(P.z, T.z, np, nt, ne);
        pair_update(P.w, T.w, np, nt, ne);
        aeP += np & M;        aoP += (np >> 3) & M;
        aeT += nt & M;        aoT += (nt >> 3) & M;
        aeE += ne & M;        aoE += (ne >> 3) & M;
    }

    // Widen to u16-packed (class 2j | class 2j+1 << 16) and wave-reduce.
    // Wave sums per half <= 64*32 = 2048: no cross-carry.
    const int wid  = tid >> 6;
    const int lane = tid & 63;
    #pragma unroll
    for (int j = 0; j < 10; ++j) {
        const int sh = 6 * j;
        u32 sP = (u32)((aeP >> sh) & 63) | ((u32)((aoP >> sh) & 63) << 16);
        u32 sT = (u32)((aeT >> sh) & 63) | ((u32)((aoT >> sh) & 63) << 16);
        u32 sE = (u32)((aeE >> sh) & 63) | ((u32)((aoE >> sh) & 63) << 16);
        #pragma unroll
        for (int d = 32; d >= 1; d >>= 1) {
            sP += __shfl_down(sP, d, 64);
            sT += __shfl_down(sT, d, 64);
            sE += __shfl_down(sE, d, 64);
        }
        if (lane == 0) {
            swave[wid][j]      = sP;
            swave[wid][10 + j] = sT;
            swave[wid][20 + j] = sE;
        }
    }
    __syncthreads();

    // Block sums per half <= 4*2048 = 8192 (u16-safe). Plain store, own slot.
    if (tid < 30) {
        u32 s = swave[0][tid] + swave[1][tid] + swave[2][tid] + swave[3][tid];
        part[tid * BLOCKS + blockIdx.x] = s;
    }
}

// Stage 2 (fused reduce + finalize): 1 block, 1024 threads; half-wave per
// packed column, vectorized non-temporal v4u reads of the contiguous row.
__global__ __launch_bounds__(1024) void dice_reduce_final(
    const u32* __restrict__ part, float* __restrict__ out)
{
    __shared__ u32 cls[64];               // 60 counters (hist*20 + class)
    const int tid = threadIdx.x;
    const int j   = tid >> 5;             // packed column 0..31 (use <30)
    const int l   = tid & 31;
    if (j < 30) {
        const v4u* row = (const v4u*)(part + j * BLOCKS);
        u32 lo = 0, hi = 0;
        #pragma unroll
        for (int i = 0; i < BLOCKS / 128; ++i) {      // 16 x 16B per lane
            v4u v = __builtin_nontemporal_load(&row[l + i * 32]);
            lo += (v.x & 0xFFFFu) + (v.y & 0xFFFFu) + (v.z & 0xFFFFu) + (v.w & 0xFFFFu);
            hi += (v.x >> 16)     + (v.y >> 16)     + (v.z >> 16)     + (v.w >> 16);
        }
        #pragma unroll
        for (int d = 16; d >= 1; d >>= 1) {
            lo += __shfl_down(lo, d, 32);
            hi += __shfl_down(hi, d, 32);
        }
        if (l == 0) {
            const int hist = j / 10, kk = j % 10;
            cls[hist * NC + 2 * kk]     = lo;   // class 2k
            cls[hist * NC + 2 * kk + 1] = hi;   // class 2k+1
        }
    }
    __syncthreads();
    if (tid < 64) {
        const int c = tid;                // classes 1..19 contribute
        float contrib = 0.0f;
        if (c >= 1 && c < NC) {
            float pc = (float)cls[c];
            float tc = (float)cls[NC + c];
            float tp = (float)cls[2 * NC + c];
            contrib = 2.0f * tp / (pc + tc + EPSF);
        }
        #pragma unroll
        for (int d = 32; d >= 1; d >>= 1) contrib += __shfl_down(contrib, d, 64);
        if (tid == 0) out[0] = contrib * (1.0f / 19.0f);
    }
}

// Generic fallback (any n divisible by 4): joint-histogram kernel w/ atomics.
__global__ __launch_bounds__(THREADS) void dice_joint(
    const int* __restrict__ pred, const int* __restrict__ tgt,
    u32* __restrict__ gc, long long n4)
{
    __shared__ u32 h[4 * NC * NC];
    const int tid = threadIdx.x;
    for (int k = tid; k < 4 * NC * NC; k += THREADS) h[k] = 0u;
    __syncthreads();
    u32* hw = &h[(tid >> 6) * NC * NC];
    const int4* p4 = (const int4*)pred;
    const int4* t4 = (const int4*)tgt;
    const long long stride = (long long)2048 * THREADS;
    for (long long i = (long long)blockIdx.x * THREADS + tid; i < n4; i += stride) {
        int4 Pv = p4[i];
        int4 Tv = t4[i];
        atomicAdd(&hw[Pv.x * NC + Tv.x], 1u);
        atomicAdd(&hw[Pv.y * NC + Tv.y], 1u);
        atomicAdd(&hw[Pv.z * NC + Tv.z], 1u);
        atomicAdd(&hw[Pv.w * NC + Tv.w], 1u);
    }
    __syncthreads();
    for (int k = tid; k < NC * NC; k += THREADS)
        h[k] = h[k] + h[NC*NC + k] + h[2*NC*NC + k] + h[3*NC*NC + k];
    __syncthreads();
    if (tid < 3 * (NC - 1)) {
        const int which = tid / (NC - 1);
        const int c     = tid % (NC - 1) + 1;
        u32 s = 0;
        if (which == 0)      { for (int t = 0; t < NC; ++t) s += h[c * NC + t]; }
        else if (which == 1) { for (int p = 0; p < NC; ++p) s += h[p * NC + c]; }
        else                 { s = h[c * NC + c]; }
        atomicAdd(&gc[which * NC + c], s);
    }
}

__global__ void dice_final(const u32* __restrict__ gc, float* __restrict__ out)
{
    const int c = threadIdx.x;
    float contrib = 0.0f;
    if (c >= 1 && c < NC) {
        float pc = (float)gc[c];
        float tc = (float)gc[NC + c];
        float tp = (float)gc[2 * NC + c];
        contrib = 2.0f * tp / (pc + tc + EPSF);
    }
    #pragma unroll
    for (int d = 32; d >= 1; d >>= 1) contrib += __shfl_down(contrib, d, 64);
    if (c == 0) out[0] = contrib * (1.0f / 19.0f);
}

extern "C" void kernel_launch(void* const* d_in, const int* in_sizes, int n_in,
                              void* d_out, int out_size, void* d_ws, size_t ws_size,
                              hipStream_t stream) {
    const int* pred = (const int*)d_in[0];
    const int* tgt  = (const int*)d_in[1];
    u32* gc   = (u32*)d_ws;
    u32* part = (u32*)d_ws + PART_OFF;

    const int n  = in_sizes[0];        // 16,777,216
    const int n4 = n >> 2;             // 4,194,304 == BLOCKS*THREADS*GRAN

    if (n4 == BLOCKS * THREADS * GRAN && ws_size >= (size_t)WS_NEEDED) {
        // Atomic-free 2-launch path: partials fully overwritten each call.
        dice_slice<<<BLOCKS, THREADS, 0, stream>>>(pred, tgt, part);
        dice_reduce_final<<<1, 1024, 0, stream>>>(part, (float*)d_out);
    } else {
        (void)hipMemsetAsync(d_ws, 0, 3 * NC * sizeof(u32), stream);
        dice_joint<<<2048, THREADS, 0, stream>>>(pred, tgt, gc, (long long)n4);
        dice_final<<<1, 64, 0, stream>>>(gc, (float*)d_out);
    }
}